// Round 8
// baseline (103.855 us; speedup 1.0000x reference)
//
#include <hip/hip_runtime.h>
#include <hip/hip_bf16.h>

#define NA 4
#define BB 256
#define DDm 128
#define KKm 256   // hidden = 2*D

typedef __attribute__((ext_vector_type(4))) float f32x4;
typedef __attribute__((ext_vector_type(4))) unsigned int u32x4;
typedef __attribute__((ext_vector_type(8))) short bf16x8;

// RNE float -> bf16 bits
__device__ __forceinline__ unsigned int f2bf(float f) {
  unsigned int bits = __builtin_bit_cast(unsigned int, f);
  unsigned int lsb = (bits >> 16) & 1u;
  return (bits + 0x7fffu + lsb) >> 16;
}

// prep: W1T fp32 [a][k] (coalesced phase-1 reads) + fragment-ordered bf16 Wf.
// Wf chunk layout: byte = ((kc*8 + rb)*64 + lr*4 + g)*16 + ke*2
//   holds bf16 W1T[row = rb*16+lr][k = kc*32 + g*8 + ke]
// -> at each (kc, rb) a wave's 64 lanes (g=lane>>4, lr=lane&15) read one
//    contiguous aligned 1KB chunk: perfect coalescing, no LDS needed.
__global__ __launch_bounds__(256) void prep_kernel(const float* __restrict__ W1,
                                                   unsigned short* __restrict__ Wf_g,
                                                   float* __restrict__ W1T) {
  int blk = blockIdx.x;          // 32 blocks = 4 agents x 8 chunks
  int i = blk >> 3;
  int chunk = blk & 7;
  const float* W1i = W1 + i * KKm * DDm;
  char* Wfi = (char*)(Wf_g + i * 32768);
  float* W1Ti = W1T + i * DDm * KKm;
  int base = chunk * 4096;
  for (int idx = base + threadIdx.x; idx < base + 4096; idx += 256) {
    int a = idx >> 8;            // 0..127 (z-dim / row)
    int k = idx & 255;           // 0..255 (hidden)
    float v = W1i[k * DDm + a];
    W1Ti[a * KKm + k] = v;
    int kc = k >> 5, g = (k >> 3) & 3, ke = k & 7, rb = a >> 4, lr = a & 15;
    size_t off = (size_t)(((kc * 8 + rb) * 64 + lr * 4 + g) * 16 + ke * 2);
    *(unsigned short*)(Wfi + off) = (unsigned short)f2bf(v);
  }
}

// One block = one (i,j) pair x ONE batch. 4 waves; wave = 32x128 rows.
// No LDS W-tile: fragments load coalesced from L1/L2-resident Wf.
// Diagonal pairs stream zeros. 4 blocks/CU target.
__global__ __launch_bounds__(256, 4) void hess_kernel(
    const float* __restrict__ z_all, const float* __restrict__ b1,
    const float* __restrict__ W2, const unsigned short* __restrict__ Wf_g,
    const float* __restrict__ W1T, float* __restrict__ out) {
  __shared__ float s_lds[KKm];   // 1KB scale vector

  int t = threadIdx.x;
  int blk = blockIdx.x;
  int pair = blk >> 8;            // 0..15
  int b = blk & 255;              // batch
  int i = pair >> 2;
  int j = pair & 3;
  float* op0 = out + (((size_t)pair * BB + b) << 14);

  if (i == j) {
    f32x4 z4 = (f32x4){0.f, 0.f, 0.f, 0.f};
    f32x4* zp = (f32x4*)op0;
#pragma unroll
    for (int q = 0; q < 16; ++q) zp[q * 256 + t] = z4;
    return;
  }

  // --- phase 1: s_k for this batch (fp32, coalesced over k=t)
  {
    const float* w = W1T + i * DDm * KKm + t;                 // W1T[i][a][t]
    const float* zj = z_all + ((size_t)j * BB + b) * DDm;
    float u = b1[i * KKm + t];
#pragma unroll 8
    for (int a = 0; a < DDm; ++a) u = fmaf(w[a * KKm], zj[a], u);
    float w2v = W2[i * KKm + t];
    float h = tanhf(u);
    s_lds[t] = -2.0f * w2v * h * (1.0f - h * h);
  }
  __syncthreads();

  int wvi = t >> 6, lane = t & 63;
  int g = lane >> 4;              // k-group 0..3
  int lr = lane & 15;             // row-in-tile / col-in-tile
  int m0 = wvi * 32;              // this wave's 32 output rows

  f32x4 acc[2][8];
#pragma unroll
  for (int mt = 0; mt < 2; ++mt)
#pragma unroll
    for (int nt = 0; nt < 8; ++nt) acc[mt][nt] = (f32x4){0.f, 0.f, 0.f, 0.f};

  const char* wf = (const char*)(Wf_g + i * 32768) + (lr * 4 + g) * 16;

  for (int kc = 0; kc < 8; ++kc) {
    const char* base = wf + kc * 8192;
    // A-chunks: this wave's 2 row-blocks (rb = wvi*2, wvi*2+1), scaled by s
    const char* abase = base + wvi * 2048;
    u32x4 a0 = *(const u32x4*)abase;
    u32x4 a1 = *(const u32x4*)(abase + 1024);

    const f32x4* sp = (const f32x4*)&s_lds[kc * 32 + g * 8];
    f32x4 sA = sp[0], sB = sp[1];
    float sv[8] = {sA[0], sA[1], sA[2], sA[3], sB[0], sB[1], sB[2], sB[3]};

    bf16x8 afr[2];
#pragma unroll
    for (int mt = 0; mt < 2; ++mt) {
      u32x4 wq = mt ? a1 : a0;
      u32x4 aq;
#pragma unroll
      for (int q = 0; q < 4; ++q) {
        float lo = __builtin_bit_cast(float, wq[q] << 16) * sv[2 * q];
        float hi = __builtin_bit_cast(float, wq[q] & 0xffff0000u) * sv[2 * q + 1];
        unsigned int lb = __builtin_bit_cast(unsigned short, (__bf16)lo);
        unsigned int hb = __builtin_bit_cast(unsigned short, (__bf16)hi);
        aq[q] = lb | (hb << 16);   // lo -> low half
      }
      afr[mt] = __builtin_bit_cast(bf16x8, aq);
    }

    // B-chunks streamed per column-tile (keeps VGPR liveness low; compiler
    // software-pipelines the loads)
#pragma unroll
    for (int nt = 0; nt < 8; ++nt) {
      bf16x8 bfr = *(const bf16x8*)(base + nt * 1024);
      acc[0][nt] = __builtin_amdgcn_mfma_f32_16x16x32_bf16(afr[0], bfr, acc[0][nt], 0, 0, 0);
      acc[1][nt] = __builtin_amdgcn_mfma_f32_16x16x32_bf16(afr[1], bfr, acc[1][nt], 0, 0, 0);
    }
  }

  // --- store (R3 pattern): row = m0 + mt*16 + g*4 + q, col = nt*16 + lr
#pragma unroll
  for (int mt = 0; mt < 2; ++mt) {
    int rbase = m0 + mt * 16 + g * 4;
#pragma unroll
    for (int nt = 0; nt < 8; ++nt) {
      int col = nt * 16 + lr;
#pragma unroll
      for (int q = 0; q < 4; ++q) op0[(size_t)(rbase + q) * DDm + col] = acc[mt][nt][q];
    }
  }
}

extern "C" void kernel_launch(void* const* d_in, const int* in_sizes, int n_in,
                              void* d_out, int out_size, void* d_ws, size_t ws_size,
                              hipStream_t stream) {
  const float* z_all = (const float*)d_in[0];
  const float* W1 = (const float*)d_in[1];
  const float* b1 = (const float*)d_in[2];
  const float* W2 = (const float*)d_in[3];
  // b2 (d_in[4]) does not affect the Hessian
  float* out = (float*)d_out;

  unsigned short* Wf_g = (unsigned short*)d_ws;            // 256KB fragment-ordered bf16
  float* W1T = (float*)((char*)d_ws + 262144);             // 512KB fp32 transpose

  prep_kernel<<<32, 256, 0, stream>>>(W1, Wf_g, W1T);
  hess_kernel<<<16 * 256, 256, 0, stream>>>(z_all, b1, W2, Wf_g, W1T, out);
}

// Round 9
// 83.880 us; speedup vs baseline: 1.2381x; 1.2381x over previous
//
#include <hip/hip_runtime.h>
#include <hip/hip_bf16.h>

#define NA 4
#define BB 256
#define DDm 128
#define KKm 256   // hidden = 2*D

typedef __attribute__((ext_vector_type(4))) float f32x4;
typedef __attribute__((ext_vector_type(4))) unsigned int u32x4;
typedef __attribute__((ext_vector_type(8))) short bf16x8;

// RNE float -> bf16 bits
__device__ __forceinline__ unsigned int f2bf(float f) {
  unsigned int bits = __builtin_bit_cast(unsigned int, f);
  unsigned int lsb = (bits >> 16) & 1u;
  return (bits + 0x7fffu + lsb) >> 16;
}

// Swizzled byte offset of (row a, k2 bytes) inside a [128][128] bf16 HALF-tile
// (row stride 256B). XOR bits 4-6 with a&7: 16-row b128 column reads are
// 2-way bank conflicts (free, m136).
__device__ __forceinline__ int swz2(int a, int k2) {
  return ((a << 8) + k2) ^ ((a & 7) << 4);
}

// prep: W1T fp32 [a][k] (coalesced phase-1 reads) + swizzled bf16 tile in TWO
// 32KB K-halves (each linearly DMA-able, swizzle pre-applied in global).
__global__ __launch_bounds__(256) void prep_kernel(const float* __restrict__ W1,
                                                   unsigned short* __restrict__ Wt_g,
                                                   float* __restrict__ W1T) {
  int blk = blockIdx.x;          // 32 blocks = 4 agents x 8 chunks
  int i = blk >> 3;
  int chunk = blk & 7;
  const float* W1i = W1 + i * KKm * DDm;
  char* Wti = (char*)(Wt_g + i * 32768);          // 64KB per agent
  float* W1Ti = W1T + i * DDm * KKm;
  int base = chunk * 4096;
  for (int idx = base + threadIdx.x; idx < base + 4096; idx += 256) {
    int a = idx >> 8;            // 0..127 (z-dim / row)
    int k = idx & 255;           // 0..255 (hidden)
    float v = W1i[k * DDm + a];
    W1Ti[a * KKm + k] = v;
    int half = k >> 7;
    int off = half * 32768 + swz2(a, (k & 127) << 1);
    *(unsigned short*)(Wti + off) = (unsigned short)f2bf(v);
  }
}

// One block = one (i,j) pair x ONE batch. 4 waves; wave = 32x128 output rows.
// LDS W-tile processed in two 32KB K-halves -> 33KB LDS -> 4 blocks/CU;
// acc[2][8]=64 VGPR -> <=128 VGPR -> 16 waves/CU (4/SIMD) for store/compute TLP.
__global__ __launch_bounds__(256, 4) void hess_kernel(
    const float* __restrict__ z_all, const float* __restrict__ b1,
    const float* __restrict__ W2, const unsigned short* __restrict__ Wt_g,
    const float* __restrict__ W1T, float* __restrict__ out) {
  __shared__ __align__(16) unsigned short Wt[16384];   // 32KB half-tile
  __shared__ __align__(16) float s_lds[KKm];           // 1KB scale vector

  int t = threadIdx.x;
  int blk = blockIdx.x;
  int pair = blk >> 8;            // 0..15
  int b = blk & 255;              // batch
  int i = pair >> 2;
  int j = pair & 3;
  float* op0 = out + (((size_t)pair * BB + b) << 14);

  if (i == j) {
    f32x4 z4 = (f32x4){0.f, 0.f, 0.f, 0.f};
    f32x4* zp = (f32x4*)op0;
#pragma unroll
    for (int q = 0; q < 16; ++q) zp[q * 256 + t] = z4;
    return;
  }

  int wvi = t >> 6, lane = t & 63;
  const char* src = (const char*)(Wt_g + i * 32768);

  // --- DMA K-half 0 (linear copy; swizzle pre-applied in global layout)
#pragma unroll
  for (int it = 0; it < 8; ++it) {
    int off = (it * 4 + wvi) * 1024;
    __builtin_amdgcn_global_load_lds(
        (const __attribute__((address_space(1))) unsigned int*)(src + off + lane * 16),
        (__attribute__((address_space(3))) unsigned int*)((char*)Wt + off),
        16, 0, 0);
  }

  // --- phase 1: s_k for this batch (fp32, coalesced over k=t) while DMA flies
  {
    const float* w = W1T + i * DDm * KKm + t;                 // W1T[i][a][t]
    const float* zj = z_all + ((size_t)j * BB + b) * DDm;
    float u = b1[i * KKm + t];
#pragma unroll 8
    for (int a = 0; a < DDm; ++a) u = fmaf(w[a * KKm], zj[a], u);
    float w2v = W2[i * KKm + t];
    float h = tanhf(u);
    s_lds[t] = -2.0f * w2v * h * (1.0f - h * h);
  }
  __syncthreads();   // drains vmcnt -> half 0 + s ready

  int g = lane >> 4;              // k-group 0..3
  int lr = lane & 15;             // row-in-tile / col-in-tile
  int m0 = wvi * 32;              // this wave's 32 output rows

  f32x4 acc[2][8];
#pragma unroll
  for (int mt = 0; mt < 2; ++mt)
#pragma unroll
    for (int nt = 0; nt < 8; ++nt) acc[mt][nt] = (f32x4){0.f, 0.f, 0.f, 0.f};

  for (int half = 0; half < 2; ++half) {
    if (half) {
      __syncthreads();   // all waves done reading half 0
#pragma unroll
      for (int it = 0; it < 8; ++it) {
        int off = (it * 4 + wvi) * 1024;
        __builtin_amdgcn_global_load_lds(
            (const __attribute__((address_space(1))) unsigned int*)(src + 32768 + off + lane * 16),
            (__attribute__((address_space(3))) unsigned int*)((char*)Wt + off),
            16, 0, 0);
      }
      __syncthreads();   // vmcnt drained before barrier -> half 1 ready
    }

#pragma unroll
    for (int kq = 0; kq < 4; ++kq) {
      int kbyte = kq * 64 + g * 16;
      const f32x4* sp = (const f32x4*)&s_lds[half * 128 + kq * 32 + g * 8];
      f32x4 sA = sp[0], sB = sp[1];
      float sv[8] = {sA[0], sA[1], sA[2], sA[3], sB[0], sB[1], sB[2], sB[3]};

      // A-fragments: s-scaled W rows (this wave's 32 rows)
      bf16x8 afr[2];
#pragma unroll
      for (int mt = 0; mt < 2; ++mt) {
        int row = m0 + mt * 16 + lr;
        u32x4 wq = *(const u32x4*)((const char*)Wt + swz2(row, kbyte));
        u32x4 aq;
#pragma unroll
        for (int q = 0; q < 4; ++q) {
          float lo = __builtin_bit_cast(float, wq[q] << 16) * sv[2 * q];
          float hi = __builtin_bit_cast(float, wq[q] & 0xffff0000u) * sv[2 * q + 1];
          unsigned int lb = __builtin_bit_cast(unsigned short, (__bf16)lo);
          unsigned int hb = __builtin_bit_cast(unsigned short, (__bf16)hi);
          aq[q] = lb | (hb << 16);   // lo -> low half
        }
        afr[mt] = __builtin_bit_cast(bf16x8, aq);
      }

      // B-fragments: unscaled W rows, stream all 8 column-tiles
#pragma unroll
      for (int nt = 0; nt < 8; ++nt) {
        int row = nt * 16 + lr;
        bf16x8 bfr = __builtin_bit_cast(
            bf16x8, *(const u32x4*)((const char*)Wt + swz2(row, kbyte)));
        acc[0][nt] = __builtin_amdgcn_mfma_f32_16x16x32_bf16(afr[0], bfr, acc[0][nt], 0, 0, 0);
        acc[1][nt] = __builtin_amdgcn_mfma_f32_16x16x32_bf16(afr[1], bfr, acc[1][nt], 0, 0, 0);
      }
    }
  }

  // --- store (R3 pattern): row = m0 + mt*16 + g*4 + q, col = nt*16 + lr
#pragma unroll
  for (int mt = 0; mt < 2; ++mt) {
    int rbase = m0 + mt * 16 + g * 4;
#pragma unroll
    for (int nt = 0; nt < 8; ++nt) {
      int col = nt * 16 + lr;
#pragma unroll
      for (int q = 0; q < 4; ++q) op0[(size_t)(rbase + q) * DDm + col] = acc[mt][nt][q];
    }
  }
}

extern "C" void kernel_launch(void* const* d_in, const int* in_sizes, int n_in,
                              void* d_out, int out_size, void* d_ws, size_t ws_size,
                              hipStream_t stream) {
  const float* z_all = (const float*)d_in[0];
  const float* W1 = (const float*)d_in[1];
  const float* b1 = (const float*)d_in[2];
  const float* W2 = (const float*)d_in[3];
  // b2 (d_in[4]) does not affect the Hessian
  float* out = (float*)d_out;

  unsigned short* Wt_g = (unsigned short*)d_ws;            // 256KB swizzled bf16 (2 halves/agent)
  float* W1T = (float*)((char*)d_ws + 262144);             // 512KB fp32 transpose

  prep_kernel<<<32, 256, 0, stream>>>(W1, Wt_g, W1T);
  hess_kernel<<<16 * 256, 256, 0, stream>>>(z_all, b1, W2, Wt_g, W1T, out);
}

// Round 10
// 69.116 us; speedup vs baseline: 1.5026x; 1.2136x over previous
//
#include <hip/hip_runtime.h>
#include <hip/hip_bf16.h>

#define NA 4
#define BB 256
#define DDm 128
#define KKm 256   // hidden = 2*D

typedef __attribute__((ext_vector_type(4))) float f32x4;
typedef __attribute__((ext_vector_type(4))) unsigned int u32x4;
typedef __attribute__((ext_vector_type(8))) short bf16x8;

// RNE float -> bf16 bits
__device__ __forceinline__ unsigned int f2bf(float f) {
  unsigned int bits = __builtin_bit_cast(unsigned int, f);
  unsigned int lsb = (bits >> 16) & 1u;
  return (bits + 0x7fffu + lsb) >> 16;
}

// Swizzled byte offset of element (row a, col k) inside a [128][256] bf16 tile.
// Row stride 512B; XOR bits 4-6 with (a&7): conflict-free b128 column reads.
__device__ __forceinline__ int swz_off(int a, int k2bytes) {
  return ((a << 9) + k2bytes) ^ ((a & 7) << 4);
}

// prep: W1T fp32 [a][k] (coalesced phase-1 reads) + swizzled bf16 W1T tile.
__global__ __launch_bounds__(256) void prep_kernel(const float* __restrict__ W1,
                                                   unsigned short* __restrict__ Wt_g,
                                                   float* __restrict__ W1T) {
  int blk = blockIdx.x;          // 32 blocks = 4 agents x 8 chunks
  int i = blk >> 3;
  int chunk = blk & 7;
  const float* W1i = W1 + i * KKm * DDm;
  char* Wti = (char*)(Wt_g + i * 32768);
  float* W1Ti = W1T + i * DDm * KKm;
  int base = chunk * 4096;
  for (int idx = base + threadIdx.x; idx < base + 4096; idx += 256) {
    int a = idx >> 8;            // 0..127 (z-dim)
    int k = idx & 255;           // 0..255 (hidden)
    float v = W1i[k * DDm + a];
    W1Ti[a * KKm + k] = v;
    *(unsigned short*)(Wti + swz_off(a, k << 1)) = (unsigned short)f2bf(v);
  }
}

// Block = one (i,j) pair x 8 batches. 4 waves. ONE barrier total; after it,
// each wave streams 8 chunk-jobs (4 batches x two 32-row chunks) with
// alternating acc sets so stores drain under the next chunk's compute.
// Waves/blocks desynchronize -> continuous store traffic (breaks phase lockstep).
__global__ __launch_bounds__(256, 2) void hess_kernel(
    const float* __restrict__ z_all, const float* __restrict__ b1,
    const float* __restrict__ W2, const unsigned short* __restrict__ Wt_g,
    const float* __restrict__ W1T, float* __restrict__ out) {
  __shared__ __align__(16) unsigned short Wt[32768];   // 64KB swizzled bf16 W1_i^T
  __shared__ __align__(16) float s_lds[8][KKm];        // 8KB: per-batch scale vectors

  int t = threadIdx.x;
  int blk = blockIdx.x;
  int pair = blk >> 5;            // 0..15
  int bgrp = blk & 31;            // batch group (8 batches)
  int i = pair >> 2;
  int j = pair & 3;

  if (i == j) {
    // zero 8 batches' diagonal blocks: 512KB contiguous
    f32x4* zp = (f32x4*)(out + (((size_t)pair * BB + bgrp * 8) << 14));
    f32x4 z4 = (f32x4){0.f, 0.f, 0.f, 0.f};
#pragma unroll
    for (int q = 0; q < 128; ++q) zp[q * 256 + t] = z4;
    return;
  }

  // --- issue async staging of W-tile (linear copy; swizzle pre-applied in global)
  {
    int wv = t >> 6, lane = t & 63;
    const char* src = (const char*)(Wt_g + i * 32768);
#pragma unroll
    for (int it = 0; it < 16; ++it) {
      int off = (it * 4 + wv) * 1024;
      __builtin_amdgcn_global_load_lds(
          (const __attribute__((address_space(1))) unsigned int*)(src + off + lane * 16),
          (__attribute__((address_space(3))) unsigned int*)((char*)Wt + off),
          16, 0, 0);
    }
  }

  // --- phase 1: s_k for all 8 batches (fp32, coalesced over k=t) while DMA flies
  {
    const float* w = W1T + i * DDm * KKm + t;                 // W1T[i][a][t]
    const float* zj = z_all + ((size_t)j * BB + bgrp * 8) * DDm;
    float ub = b1[i * KKm + t];
    float u[8];
#pragma unroll
    for (int v = 0; v < 8; ++v) u[v] = ub;
#pragma unroll 4
    for (int a = 0; a < DDm; ++a) {
      float wa = w[a * KKm];
#pragma unroll
      for (int v = 0; v < 8; ++v) u[v] = fmaf(wa, zj[v * DDm + a], u[v]);
    }
    float w2v = W2[i * KKm + t];
#pragma unroll
    for (int v = 0; v < 8; ++v) {
      float h = tanhf(u[v]);
      s_lds[v][t] = -2.0f * w2v * h * (1.0f - h * h);
    }
  }
  __syncthreads();   // drains vmcnt too -> Wt + s ready. LAST barrier.

  int wvi = t >> 6, lane = t & 63;
  int g = lane >> 4;              // k-group 0..3
  int lr = lane & 15;             // row-in-tile / col-in-tile
  int bset = wvi >> 1;            // waves 0,1 -> batches 0-3; waves 2,3 -> 4-7
  int rb0 = (wvi & 1) * 64;       // row half within batch

  f32x4 accA[2][8], accB[2][8];

  // One 32-row chunk: full kc-loop + store (R3 store pattern).
  auto do_chunk = [&](f32x4 (&acc)[2][8], int rowbase, const float* sb, float* op) {
#pragma unroll
    for (int mt = 0; mt < 2; ++mt)
#pragma unroll
      for (int nt = 0; nt < 8; ++nt) acc[mt][nt] = (f32x4){0.f, 0.f, 0.f, 0.f};

    for (int kc = 0; kc < 8; ++kc) {
      int kbyte = kc * 64 + g * 16;
      const f32x4* sp = (const f32x4*)&sb[kc * 32 + g * 8];
      f32x4 sA = sp[0], sB = sp[1];
      float sv[8] = {sA[0], sA[1], sA[2], sA[3], sB[0], sB[1], sB[2], sB[3]};

      bf16x8 afr[2];
#pragma unroll
      for (int mt = 0; mt < 2; ++mt) {
        int row = rowbase + mt * 16 + lr;
        u32x4 wq = *(const u32x4*)((const char*)Wt + swz_off(row, kbyte));
        u32x4 aq;
#pragma unroll
        for (int q = 0; q < 4; ++q) {
          float lo = __builtin_bit_cast(float, wq[q] << 16) * sv[2 * q];
          float hi = __builtin_bit_cast(float, wq[q] & 0xffff0000u) * sv[2 * q + 1];
          unsigned int lb = __builtin_bit_cast(unsigned short, (__bf16)lo);
          unsigned int hb = __builtin_bit_cast(unsigned short, (__bf16)hi);
          aq[q] = lb | (hb << 16);   // lo -> low half
        }
        afr[mt] = __builtin_bit_cast(bf16x8, aq);
      }

#pragma unroll
      for (int nt = 0; nt < 8; ++nt) {
        int row = nt * 16 + lr;
        bf16x8 bfr = __builtin_bit_cast(
            bf16x8, *(const u32x4*)((const char*)Wt + swz_off(row, kbyte)));
        acc[0][nt] = __builtin_amdgcn_mfma_f32_16x16x32_bf16(afr[0], bfr, acc[0][nt], 0, 0, 0);
        acc[1][nt] = __builtin_amdgcn_mfma_f32_16x16x32_bf16(afr[1], bfr, acc[1][nt], 0, 0, 0);
      }
    }

#pragma unroll
    for (int mt = 0; mt < 2; ++mt) {
      int rbase = rowbase + mt * 16 + g * 4;
#pragma unroll
      for (int nt = 0; nt < 8; ++nt) {
        int col = nt * 16 + lr;
#pragma unroll
        for (int q = 0; q < 4; ++q) op[(size_t)(rbase + q) * DDm + col] = acc[mt][nt][q];
      }
    }
  };

  for (int bb = 0; bb < 4; ++bb) {
    int bloc = bset * 4 + bb;                    // batch within block (0..7)
    const float* sb = &s_lds[bloc][0];
    float* op = out + (((size_t)pair * BB + bgrp * 8 + bloc) << 14);
    do_chunk(accA, rb0, sb, op);                 // rows [rb0, rb0+32)
    do_chunk(accB, rb0 + 32, sb, op);            // rows [rb0+32, rb0+64)
  }
}

extern "C" void kernel_launch(void* const* d_in, const int* in_sizes, int n_in,
                              void* d_out, int out_size, void* d_ws, size_t ws_size,
                              hipStream_t stream) {
  const float* z_all = (const float*)d_in[0];
  const float* W1 = (const float*)d_in[1];
  const float* b1 = (const float*)d_in[2];
  const float* W2 = (const float*)d_in[3];
  // b2 (d_in[4]) does not affect the Hessian
  float* out = (float*)d_out;

  unsigned short* Wt_g = (unsigned short*)d_ws;            // 256KB swizzled bf16
  float* W1T = (float*)((char*)d_ws + 262144);             // 512KB fp32 transpose

  prep_kernel<<<32, 256, 0, stream>>>(W1, Wt_g, W1T);
  hess_kernel<<<16 * 32, 256, 0, stream>>>(z_all, b1, W2, Wt_g, W1T, out);
}